// Round 7
// baseline (38.679 us; speedup 1.0000x reference)
//
#include <hip/hip_runtime.h>
#include <hip/hip_bf16.h>

#define N_SIDE 14
#define N_PATCH (N_SIDE * N_SIDE)   // 196
#define D_BB 384
#define DQ_BB (D_BB / 4)             // 96 float4 per cell
#define D_MODEL 512
#define CQ (D_MODEL / 4)             // 128 col-quads
#define BT_TOTAL 2048
#define LN_EPS 1e-5f
#define ROWS 8                       // rows per gemm block
#define KP 8                         // K partitions per gemm block
#define KCHUNK (D_BB / KP)           // 48
#define GROUPS 4                     // cell groups per pool sub-block
#define SPLIT 2                      // pool sub-blocks per bt (disjoint outputs)
#define ESTRIDE (GROUPS * SPLIT)     // 8 effective groups

__device__ __forceinline__ void fma4(float4& a, float s, const float4& wv) {
    a.x = fmaf(s, wv.x, a.x);
    a.y = fmaf(s, wv.y, a.y);
    a.z = fmaf(s, wv.z, a.z);
    a.w = fmaf(s, wv.w, a.w);
}

__device__ __forceinline__ void add4(float4& a, const float4& b) {
    a.x += b.x; a.y += b.y; a.z += b.z; a.w += b.w;
}

__device__ __forceinline__ void box_params(const float* __restrict__ bboxes, int bt,
                                           int& x1, int& y1, int& wd, int& total) {
    const float bx1 = bboxes[bt * 4 + 0];
    const float by1 = bboxes[bt * 4 + 1];
    const float bx2 = bboxes[bt * 4 + 2];
    const float by2 = bboxes[bt * 4 + 3];
    // match reference exactly: clip -> trunc/ceil -> clip -> max
    x1 = (int)fminf(fmaxf(bx1 * (float)N_SIDE, 0.f), (float)(N_SIDE - 1));
    y1 = (int)fminf(fmaxf(by1 * (float)N_SIDE, 0.f), (float)(N_SIDE - 1));
    int x2 = (int)fminf(fmaxf(ceilf(fminf(fmaxf(bx2 * (float)N_SIDE, 0.f), (float)N_SIDE)), 1.f), (float)N_SIDE);
    int y2 = (int)fminf(fmaxf(ceilf(fminf(fmaxf(by2 * (float)N_SIDE, 0.f), (float)N_SIDE)), 1.f), (float)N_SIDE);
    x2 = max(x2, x1 + 1);
    y2 = max(y2, y1 + 1);
    wd = x2 - x1;
    total = wd * (y2 - y1);
}

// ---------------- Kernel 1: ROI pool partial sums (unchanged from R6) ----------------
// grid = BT_TOTAL*SPLIT, block = 384 = 96 quads x 4 cell-groups.
__global__ __launch_bounds__(384) void pool_kernel(
    const float* __restrict__ patch,   // [BT,196,384]
    const float* __restrict__ bboxes,  // [BT,4]
    float* __restrict__ pooled)        // [SPLIT,BT,384] raw partial sums
{
    const int bid = blockIdx.x;
    const int bt  = bid >> 1;
    const int s   = bid & 1;
    const int t   = threadIdx.x;
    const int qd  = t % DQ_BB;              // channel quad 0..95
    const int g   = t / DQ_BB;              // cell group 0..3
    const int e   = s * GROUPS + g;         // effective group 0..7

    int x1, y1, wd, total;
    box_params(bboxes, bt, x1, y1, wd, total);
    const float inv_wd = 1.f / (float)wd;
    const int cell0 = y1 * N_SIDE + x1;

    const float4* __restrict__ base = (const float4*)patch + (size_t)bt * N_PATCH * DQ_BB + qd;

    // flattened cell c -> grid offset (exact: (c+0.5)/wd is never near an integer)
    auto cell_off = [&](int c) -> size_t {
        const int y = (int)(((float)c + 0.5f) * inv_wd);
        const int x = c - y * wd;
        return (size_t)(cell0 + y * N_SIDE + x) * DQ_BB;
    };

    float4 acc = make_float4(0.f, 0.f, 0.f, 0.f);
    int c = e;
    // 4-deep: issue 4 independent loads, then accumulate
    for (; c + 3 * ESTRIDE < total; c += 4 * ESTRIDE) {
        const float4 v0 = base[cell_off(c)];
        const float4 v1 = base[cell_off(c + ESTRIDE)];
        const float4 v2 = base[cell_off(c + 2 * ESTRIDE)];
        const float4 v3 = base[cell_off(c + 3 * ESTRIDE)];
        acc.x += (v0.x + v1.x) + (v2.x + v3.x);
        acc.y += (v0.y + v1.y) + (v2.y + v3.y);
        acc.z += (v0.z + v1.z) + (v2.z + v3.z);
        acc.w += (v0.w + v1.w) + (v2.w + v3.w);
    }
    for (; c < total; c += ESTRIDE) {
        const float4 v = base[cell_off(c)];
        acc.x += v.x; acc.y += v.y; acc.z += v.z; acc.w += v.w;
    }

    __shared__ float4 part[GROUPS][DQ_BB];   // 6 KB
    part[g][qd] = acc;
    __syncthreads();

    if (t < DQ_BB) {
        float4 sm = part[0][t];
#pragma unroll
        for (int p = 1; p < GROUPS; ++p) add4(sm, part[p][t]);
        ((float4*)pooled)[((size_t)s * BT_TOTAL + bt) * DQ_BB + t] = sm;
    }
}

// ---------------- Kernel 2: GEMM (sums @ W)/count + b + LayerNorm + vis blend ----------------
// grid = 256, block = 1024 = 128 col-quads x 8 K-partitions (16 waves/CU = 4/SIMD)
__global__ __launch_bounds__(1024) void gemm_ln_kernel(
    const float* __restrict__ pooled,    // [SPLIT,BT,384] raw partial sums
    const float* __restrict__ bboxes,    // [BT,4]
    const float* __restrict__ W,         // [384,512]
    const float* __restrict__ bias,      // [512]
    const float* __restrict__ gamma,     // [512]
    const float* __restrict__ beta,      // [512]
    const float* __restrict__ mask_tok,  // [512]
    const float* __restrict__ vis,       // [BT]
    float* __restrict__ out)             // [BT,512]
{
    const int tid = threadIdx.x;
    const int p   = tid >> 7;        // 0..7 (K partition)
    const int jq  = tid & 127;       // col quad 0..127
    const int r0  = blockIdx.x * ROWS;

    __shared__ float  sp[ROWS][D_BB];        // 12 KB: the 8 summed rows
    __shared__ float4 red4[4][ROWS][CQ];     // 64 KB, reused across tree stages
    __shared__ float  lnred[2][ROWS][2];
    __shared__ float  s_invc[ROWS];

    // ---- stage pooled rows into LDS, summing the two split halves ----
    {
        const float4* pa = (const float4*)pooled + (size_t)r0 * DQ_BB;
        const float4* pb = (const float4*)pooled + ((size_t)BT_TOTAL + r0) * DQ_BB;
        float4* sp4 = (float4*)sp;
        for (int i = tid; i < ROWS * DQ_BB; i += 1024) {
            float4 a = pa[i];
            add4(a, pb[i]);
            sp4[i] = a;
        }
    }
    if (tid < ROWS) {
        int x1, y1, wd, total;
        box_params(bboxes, r0 + tid, x1, y1, wd, total);
        s_invc[tid] = 1.f / (float)total;
    }
    __syncthreads();

    const float4* Wq = (const float4*)W;   // [384][128] float4
    float4 acc[ROWS];
#pragma unroll
    for (int r = 0; r < ROWS; ++r) acc[r] = make_float4(0.f, 0.f, 0.f, 0.f);

    const int dbase = p * KCHUNK;
#pragma unroll 2
    for (int i = 0; i < KCHUNK / 4; ++i) {
        const int d = dbase + i * 4;
        const float4 w0 = Wq[(size_t)(d + 0) * CQ + jq];
        const float4 w1 = Wq[(size_t)(d + 1) * CQ + jq];
        const float4 w2 = Wq[(size_t)(d + 2) * CQ + jq];
        const float4 w3 = Wq[(size_t)(d + 3) * CQ + jq];
#pragma unroll
        for (int r = 0; r < ROWS; ++r) {
            const float4 a = *(const float4*)&sp[r][d];   // LDS broadcast
            fma4(acc[r], a.x, w0);
            fma4(acc[r], a.y, w1);
            fma4(acc[r], a.z, w2);
            fma4(acc[r], a.w, w3);
        }
    }

    // ---- cross-partition tree reduction via LDS: 8 -> 4 -> 2 -> 1 ----
    // stage 1: p4..7 write, p0..3 add
    if (p >= 4) {
#pragma unroll
        for (int r = 0; r < ROWS; ++r) red4[p - 4][r][jq] = acc[r];
    }
    __syncthreads();
    if (p < 4) {
#pragma unroll
        for (int r = 0; r < ROWS; ++r) add4(acc[r], red4[p][r][jq]);
    }
    __syncthreads();
    // stage 2: p2..3 write, p0..1 add
    if (p == 2 || p == 3) {
#pragma unroll
        for (int r = 0; r < ROWS; ++r) red4[p - 2][r][jq] = acc[r];
    }
    __syncthreads();
    if (p < 2) {
#pragma unroll
        for (int r = 0; r < ROWS; ++r) add4(acc[r], red4[p][r][jq]);
    }
    __syncthreads();
    // stage 3: p1 writes, p0 adds
    if (p == 1) {
#pragma unroll
        for (int r = 0; r < ROWS; ++r) red4[0][r][jq] = acc[r];
    }
    __syncthreads();

    if (p == 0) {
#pragma unroll
        for (int r = 0; r < ROWS; ++r) add4(acc[r], red4[0][r][jq]);

        const float4 bj = ((const float4*)bias)[jq];
#pragma unroll
        for (int r = 0; r < ROWS; ++r) {
            const float ic = s_invc[r];
            acc[r].x = fmaf(acc[r].x, ic, bj.x);
            acc[r].y = fmaf(acc[r].y, ic, bj.y);
            acc[r].z = fmaf(acc[r].z, ic, bj.z);
            acc[r].w = fmaf(acc[r].w, ic, bj.w);
        }

        // ---- LN partial sums across 128 threads (2 waves) ----
        const int lane = tid & 63;
        const int wv   = tid >> 6;   // 0 or 1
#pragma unroll
        for (int r = 0; r < ROWS; ++r) {
            float s  = acc[r].x + acc[r].y + acc[r].z + acc[r].w;
            float s2 = acc[r].x * acc[r].x + acc[r].y * acc[r].y +
                       acc[r].z * acc[r].z + acc[r].w * acc[r].w;
#pragma unroll
            for (int off = 32; off >= 1; off >>= 1) {
                s  += __shfl_xor(s,  off);
                s2 += __shfl_xor(s2, off);
            }
            if (lane == 0) { lnred[wv][r][0] = s; lnred[wv][r][1] = s2; }
        }
    }
    __syncthreads();

    if (p == 0) {
        const float4 g4 = ((const float4*)gamma)[jq];
        const float4 b4 = ((const float4*)beta)[jq];
        const float4 m4 = ((const float4*)mask_tok)[jq];
#pragma unroll
        for (int r = 0; r < ROWS; ++r) {
            const float s    = lnred[0][r][0] + lnred[1][r][0];
            const float s2   = lnred[0][r][1] + lnred[1][r][1];
            const float mean = s * (1.f / (float)D_MODEL);
            const float var  = s2 * (1.f / (float)D_MODEL) - mean * mean;
            const float rstd = rsqrtf(var + LN_EPS);
            const float v    = vis[r0 + r];
            const float iv   = 1.f - v;
            float4 o;
            o.x = v * ((acc[r].x - mean) * rstd * g4.x + b4.x) + iv * m4.x;
            o.y = v * ((acc[r].y - mean) * rstd * g4.y + b4.y) + iv * m4.y;
            o.z = v * ((acc[r].z - mean) * rstd * g4.z + b4.z) + iv * m4.z;
            o.w = v * ((acc[r].w - mean) * rstd * g4.w + b4.w) + iv * m4.w;
            ((float4*)out)[(size_t)(r0 + r) * CQ + jq] = o;
        }
    }
}

extern "C" void kernel_launch(void* const* d_in, const int* in_sizes, int n_in,
                              void* d_out, int out_size, void* d_ws, size_t ws_size,
                              hipStream_t stream) {
    const float* patch  = (const float*)d_in[0];  // [2048,196,384]
    const float* bboxes = (const float*)d_in[1];  // [2048,4]
    const float* vis    = (const float*)d_in[2];  // [2048]
    // d_in[3] = B, d_in[4] = T (scalars, unused)
    const float* W      = (const float*)d_in[5];  // [384,512]
    const float* bias   = (const float*)d_in[6];  // [512]
    const float* gamma  = (const float*)d_in[7];  // [512]
    const float* beta   = (const float*)d_in[8];  // [512]
    const float* mtok   = (const float*)d_in[9];  // [1,512]

    float* pooled = (float*)d_ws;                 // [2,2048,384] partial sums, 6 MB
    float* out    = (float*)d_out;

    pool_kernel<<<BT_TOTAL * SPLIT, 384, 0, stream>>>(patch, bboxes, pooled);
    gemm_ln_kernel<<<BT_TOTAL / ROWS, 1024, 0, stream>>>(
        pooled, bboxes, W, bias, gamma, beta, mtok, vis, out);
}

// Round 8
// 38.190 us; speedup vs baseline: 1.0128x; 1.0128x over previous
//
#include <hip/hip_runtime.h>
#include <hip/hip_bf16.h>

#define N_SIDE 14
#define N_PATCH (N_SIDE * N_SIDE)   // 196
#define D_BB 384
#define DQ_BB (D_BB / 4)             // 96 float4 per cell row
#define D_MODEL 512
#define CQ (D_MODEL / 4)             // 128 col-quads
#define BT_TOTAL 2048
#define LN_EPS 1e-5f
#define ROWS 4                       // bt rows per block
#define KP 3                         // K partitions (384 = 3*128 threads)
#define KCHUNK (D_BB / KP)           // 128
#define PGROUPS 4                    // pool cell-groups (384 = 4*96)

__device__ __forceinline__ void fma4(float4& a, float s, const float4& wv) {
    a.x = fmaf(s, wv.x, a.x);
    a.y = fmaf(s, wv.y, a.y);
    a.z = fmaf(s, wv.z, a.z);
    a.w = fmaf(s, wv.w, a.w);
}

__device__ __forceinline__ void add4(float4& a, const float4& b) {
    a.x += b.x; a.y += b.y; a.z += b.z; a.w += b.w;
}

__device__ __forceinline__ void box_params(const float* __restrict__ bboxes, int bt,
                                           int& x1, int& y1, int& wd, int& total) {
    const float bx1 = bboxes[bt * 4 + 0];
    const float by1 = bboxes[bt * 4 + 1];
    const float bx2 = bboxes[bt * 4 + 2];
    const float by2 = bboxes[bt * 4 + 3];
    // match reference exactly: clip -> trunc/ceil -> clip -> max
    x1 = (int)fminf(fmaxf(bx1 * (float)N_SIDE, 0.f), (float)(N_SIDE - 1));
    y1 = (int)fminf(fmaxf(by1 * (float)N_SIDE, 0.f), (float)(N_SIDE - 1));
    int x2 = (int)fminf(fmaxf(ceilf(fminf(fmaxf(bx2 * (float)N_SIDE, 0.f), (float)N_SIDE)), 1.f), (float)N_SIDE);
    int y2 = (int)fminf(fmaxf(ceilf(fminf(fmaxf(by2 * (float)N_SIDE, 0.f), (float)N_SIDE)), 1.f), (float)N_SIDE);
    x2 = max(x2, x1 + 1);
    y2 = max(y2, y1 + 1);
    wd = x2 - x1;
    total = wd * (y2 - y1);
}

// Fused: ROI-pool(4 rows) -> GEMM(4x512) -> LayerNorm -> vis blend.
// grid = 512 blocks x 384 threads (2 blocks/CU: pool BW phase of one block
// overlaps gemm VALU/L2 phase of the other).
__global__ __launch_bounds__(384) void fused_kernel(
    const float* __restrict__ patch,     // [BT,196,384]
    const float* __restrict__ bboxes,    // [BT,4]
    const float* __restrict__ W,         // [384,512]
    const float* __restrict__ bias,      // [512]
    const float* __restrict__ gamma,     // [512]
    const float* __restrict__ beta,      // [512]
    const float* __restrict__ mask_tok,  // [512]
    const float* __restrict__ vis,       // [BT]
    float* __restrict__ out)             // [BT,512]
{
    const int tid = threadIdx.x;
    const int qd  = tid % DQ_BB;   // channel quad 0..95
    const int g   = tid / DQ_BB;   // pool cell-group / reduce row 0..3
    const int r0  = blockIdx.x * ROWS;

    __shared__ float  sp[ROWS][D_BB];             // 6 KB: pooled means
    __shared__ float4 part[ROWS][PGROUPS][DQ_BB]; // 24 KB
    __shared__ float4 red4[KP - 1][ROWS][CQ];     // 16 KB
    __shared__ float  lnred[2][ROWS][2];

    // ---------------- Phase 1: pool 4 rows (masked 8-deep pipeline) ----------------
    for (int r = 0; r < ROWS; ++r) {
        int x1, y1, wd, total;
        box_params(bboxes, r0 + r, x1, y1, wd, total);
        const float inv_wd = 1.f / (float)wd;
        const int cell0 = y1 * N_SIDE + x1;
        const float4* __restrict__ base =
            (const float4*)patch + (size_t)(r0 + r) * N_PATCH * DQ_BB + qd;

        auto cell_off = [&](int cidx) -> size_t {
            const int cc = min(cidx, total - 1);
            const int y  = (int)(((float)cc + 0.5f) * inv_wd);
            const int x  = cc - y * wd;
            return (size_t)(cell0 + y * N_SIDE + x) * DQ_BB;
        };

        float4 acc = make_float4(0.f, 0.f, 0.f, 0.f);
        for (int c = g; c < total; c += 8 * PGROUPS) {
            // 8 slots, stride PGROUPS cells; OOB slots re-load a valid cell, masked to 0
            const float4 v0 = base[cell_off(c)];
            const float4 v1 = base[cell_off(c + 1 * PGROUPS)];
            const float4 v2 = base[cell_off(c + 2 * PGROUPS)];
            const float4 v3 = base[cell_off(c + 3 * PGROUPS)];
            const float4 v4 = base[cell_off(c + 4 * PGROUPS)];
            const float4 v5 = base[cell_off(c + 5 * PGROUPS)];
            const float4 v6 = base[cell_off(c + 6 * PGROUPS)];
            const float4 v7 = base[cell_off(c + 7 * PGROUPS)];
            const float m1 = (c + 1 * PGROUPS < total) ? 1.f : 0.f;
            const float m2 = (c + 2 * PGROUPS < total) ? 1.f : 0.f;
            const float m3 = (c + 3 * PGROUPS < total) ? 1.f : 0.f;
            const float m4 = (c + 4 * PGROUPS < total) ? 1.f : 0.f;
            const float m5 = (c + 5 * PGROUPS < total) ? 1.f : 0.f;
            const float m6 = (c + 6 * PGROUPS < total) ? 1.f : 0.f;
            const float m7 = (c + 7 * PGROUPS < total) ? 1.f : 0.f;
            add4(acc, v0);              // slot 0 always valid (c < total)
            fma4(acc, m1, v1);
            fma4(acc, m2, v2);
            fma4(acc, m3, v3);
            fma4(acc, m4, v4);
            fma4(acc, m5, v5);
            fma4(acc, m6, v6);
            fma4(acc, m7, v7);
        }
        part[r][g][qd] = acc;
    }
    __syncthreads();

    // ---------------- Phase 2: reduce groups, apply 1/count ----------------
    {
        const int rr = g;           // 384 = 4 rows x 96 quads
        int x1, y1, wd, total;
        box_params(bboxes, r0 + rr, x1, y1, wd, total);
        const float ic = 1.f / (float)total;
        float4 s = part[rr][0][qd];
        add4(s, part[rr][1][qd]);
        add4(s, part[rr][2][qd]);
        add4(s, part[rr][3][qd]);
        s.x *= ic; s.y *= ic; s.z *= ic; s.w *= ic;
        ((float4*)sp[rr])[qd] = s;
    }
    __syncthreads();

    // ---------------- Phase 3: GEMM  (3 K-partitions x 128 col-quads) ----------------
    const int p  = tid >> 7;       // 0..2
    const int jq = tid & 127;      // col quad

    const float4* Wq = (const float4*)W;   // [384][128] float4
    float4 acc[ROWS];
#pragma unroll
    for (int r = 0; r < ROWS; ++r) acc[r] = make_float4(0.f, 0.f, 0.f, 0.f);

    const int dbase = p * KCHUNK;
#pragma unroll 2
    for (int i = 0; i < KCHUNK / 4; ++i) {
        const int d = dbase + i * 4;
        const float4 w0 = Wq[(size_t)(d + 0) * CQ + jq];
        const float4 w1 = Wq[(size_t)(d + 1) * CQ + jq];
        const float4 w2 = Wq[(size_t)(d + 2) * CQ + jq];
        const float4 w3 = Wq[(size_t)(d + 3) * CQ + jq];
#pragma unroll
        for (int r = 0; r < ROWS; ++r) {
            const float4 a = *(const float4*)&sp[r][d];   // LDS broadcast
            fma4(acc[r], a.x, w0);
            fma4(acc[r], a.y, w1);
            fma4(acc[r], a.z, w2);
            fma4(acc[r], a.w, w3);
        }
    }

    // ---------------- Phase 4: cross-partition reduce (3 -> 1) ----------------
    if (p != 0) {
#pragma unroll
        for (int r = 0; r < ROWS; ++r) red4[p - 1][r][jq] = acc[r];
    }
    __syncthreads();

    if (p == 0) {
#pragma unroll
        for (int r = 0; r < ROWS; ++r) {
            add4(acc[r], red4[0][r][jq]);
            add4(acc[r], red4[1][r][jq]);
        }
        const float4 bj = ((const float4*)bias)[jq];
#pragma unroll
        for (int r = 0; r < ROWS; ++r) add4(acc[r], bj);

        // ---- LN partial sums across 128 threads (2 waves) ----
        const int lane = tid & 63;
        const int wv   = tid >> 6;   // 0 or 1
#pragma unroll
        for (int r = 0; r < ROWS; ++r) {
            float s  = acc[r].x + acc[r].y + acc[r].z + acc[r].w;
            float s2 = acc[r].x * acc[r].x + acc[r].y * acc[r].y +
                       acc[r].z * acc[r].z + acc[r].w * acc[r].w;
#pragma unroll
            for (int off = 32; off >= 1; off >>= 1) {
                s  += __shfl_xor(s,  off);
                s2 += __shfl_xor(s2, off);
            }
            if (lane == 0) { lnred[wv][r][0] = s; lnred[wv][r][1] = s2; }
        }
    }
    __syncthreads();

    // ---------------- Phase 5: normalize + blend + store ----------------
    if (p == 0) {
        const float4 g4 = ((const float4*)gamma)[jq];
        const float4 b4 = ((const float4*)beta)[jq];
        const float4 m4 = ((const float4*)mask_tok)[jq];
#pragma unroll
        for (int r = 0; r < ROWS; ++r) {
            const float s    = lnred[0][r][0] + lnred[1][r][0];
            const float s2   = lnred[0][r][1] + lnred[1][r][1];
            const float mean = s * (1.f / (float)D_MODEL);
            const float var  = s2 * (1.f / (float)D_MODEL) - mean * mean;
            const float rstd = rsqrtf(var + LN_EPS);
            const float v    = vis[r0 + r];
            const float iv   = 1.f - v;
            float4 o;
            o.x = v * ((acc[r].x - mean) * rstd * g4.x + b4.x) + iv * m4.x;
            o.y = v * ((acc[r].y - mean) * rstd * g4.y + b4.y) + iv * m4.y;
            o.z = v * ((acc[r].z - mean) * rstd * g4.z + b4.z) + iv * m4.z;
            o.w = v * ((acc[r].w - mean) * rstd * g4.w + b4.w) + iv * m4.w;
            ((float4*)out)[(size_t)(r0 + r) * CQ + jq] = o;
        }
    }
}

extern "C" void kernel_launch(void* const* d_in, const int* in_sizes, int n_in,
                              void* d_out, int out_size, void* d_ws, size_t ws_size,
                              hipStream_t stream) {
    const float* patch  = (const float*)d_in[0];  // [2048,196,384]
    const float* bboxes = (const float*)d_in[1];  // [2048,4]
    const float* vis    = (const float*)d_in[2];  // [2048]
    // d_in[3] = B, d_in[4] = T (scalars, unused)
    const float* W      = (const float*)d_in[5];  // [384,512]
    const float* bias   = (const float*)d_in[6];  // [512]
    const float* gamma  = (const float*)d_in[7];  // [512]
    const float* beta   = (const float*)d_in[8];  // [512]
    const float* mtok   = (const float*)d_in[9];  // [1,512]

    float* out = (float*)d_out;

    fused_kernel<<<BT_TOTAL / ROWS, 384, 0, stream>>>(
        patch, bboxes, W, bias, gamma, beta, mtok, vis, out);
}